// Round 1
// baseline (3419.298 us; speedup 1.0000x reference)
//
#include <hip/hip_runtime.h>
#include <stdint.h>

#define B_ 4
#define N_ 256
#define H_ 192
#define H3_ 576
#define F_ 64
#define SH_ 12      // hidden per slice (16 slices)
#define SC_ 36      // 3 gates * SH_
#define MVT_ 144    // 9 col-groups * 16 k-chunks

// ---- workspace layout (32-bit words) ----
#define H0_OFF   0u
#define ZC_OFF   1024u
#define HL_OFF   2048u
#define SL_OFF   (HL_OFF + 262144u)
#define AB_OFF   (SL_OFF + 262144u)
#define AN_OFF   (AB_OFF + 8192u)
#define TG_OFF   (AN_OFF + 8192u)
#define PL_OFF   (TG_OFF + 8192u)
#define PC_OFF   (PL_OFF + 65536u)
#define DG_OFF   (PC_OFF + 1024u)
#define G_OFF    (DG_OFF + 1024u)
#define C_OFF    (G_OFF + 196608u)
#define CL_OFF   (C_OFF + 196608u)
#define CC_OFF   (CL_OFF + 65536u)

#define AB64 (AB_OFF/2)
#define AN64 (AN_OFF/2)
#define TG64 (TG_OFF/2)

#define NF_OUT 262144u
#define LL_OUT 327680u

__device__ __forceinline__ float sigm_(float x){ return 1.0f/(1.0f + __expf(-x)); }
__device__ __forceinline__ float tanh_(float x){
  float ax = fabsf(x);
  float e = __expf(-2.0f*ax);
  float t = (1.0f - e)/(1.0f + e);
  return x < 0.0f ? -t : t;
}

__device__ __forceinline__ unsigned hline_(int b,int t,int s){ return HL_OFF + (unsigned)((b*N_+t)*16+s)*16u; }
__device__ __forceinline__ unsigned sline_(int b,int t,int s){ return SL_OFF + (unsigned)((b*N_+t)*16+s)*16u; }

// y[36] = x[192] @ Wslice ; 144 threads: g=tid>>4 owns 4 cols, kc=tid&15 owns 12 k's.
// Butterfly shfl over the 16-lane kc group leaves the FULL sum in every lane.
__device__ __forceinline__ void mv36_(const float* x, const float (&w)[12][4], int kc, float acc[4]){
  acc[0]=0.f; acc[1]=0.f; acc[2]=0.f; acc[3]=0.f;
  #pragma unroll
  for (int i=0;i<12;i++){
    float xv = x[kc*12+i];
    acc[0] += xv*w[i][0];
    acc[1] += xv*w[i][1];
    acc[2] += xv*w[i][2];
    acc[3] += xv*w[i][3];
  }
  #pragma unroll
  for (int m=1;m<16;m<<=1){
    acc[0] += __shfl_xor(acc[0], m);
    acc[1] += __shfl_xor(acc[1], m);
    acc[2] += __shfl_xor(acc[2], m);
    acc[3] += __shfl_xor(acc[3], m);
  }
}

// ---------- prologue A: h0 = tanh(z@W_init+b_init), zc = z@W1c+b1, zero ll ----------
__global__ void k_p0a(const float* __restrict__ z, const float* __restrict__ Winit,
    const float* __restrict__ binit, const float* __restrict__ W1, const float* __restrict__ b1,
    float* ws, float* out)
{
  int b = blockIdx.x; int tid = threadIdx.x;
  __shared__ float zs[H_];
  zs[tid] = z[b*H_ + tid];
  __syncthreads();
  float a0=0.f, a1=0.f;
  for (int k=0;k<H_;k++){
    float zv = zs[k];
    a0 += zv * Winit[(size_t)k*H_ + tid];
    a1 += zv * W1[(size_t)(2*H_ + k)*H_ + tid];   // W1c rows 384..575
  }
  ws[H0_OFF + b*H_ + tid] = tanh_(a0 + binit[tid]);
  ws[ZC_OFF + b*H_ + tid] = a1 + b1[tid];
  if (b==0 && tid==0) out[LL_OUT] = 0.0f;
}

// ---------- prologue B: per-row parent lists, tgt bitmasks, deg, gen zeroing ----------
__global__ void k_p0b(const float* __restrict__ tgt, float* ws)
{
  int t = blockIdx.x, b = blockIdx.y, lane = threadIdx.x;
  uint32_t* wsu = (uint32_t*)ws;
  unsigned long long* ws64 = (unsigned long long*)ws;
  if (lane < 16){
    wsu[hline_(b,t,lane) + 12] = 0u;   // zero generation words (ws is poisoned each launch)
    wsu[sline_(b,t,lane) + 12] = 0u;
  }
  if (t == 0 && lane < 4) ws64[AB64 + (size_t)(b*N_)*4 + lane] = 0ULL;  // A row 0 = 0
  const float* row = tgt + ((size_t)(b*N_) + t)*N_;
  uint8_t* pl = ((uint8_t*)&wsu[PL_OFF]) + (size_t)(b*N_ + t)*N_;
  int cnt = 0;
  #pragma unroll
  for (int m=0;m<4;m++){
    float v = row[m*64 + lane];
    bool p = (v != 0.0f);
    unsigned long long bw = __ballot(p);
    if (lane == 0) ws64[TG64 + (size_t)(b*N_+t)*4 + m] = bw;
    if (p){
      int pos = cnt + (int)__popcll(bw & ((1ULL<<lane)-1ULL));
      pl[pos] = (uint8_t)(m*64 + lane);
    }
    cnt += (int)__popcll(bw);
  }
  if (lane == 0){
    wsu[PC_OFF + b*N_ + t] = (uint32_t)cnt;
    ws[DG_OFF + b*N_ + t] = 1.0f / fmaxf((float)cnt, 1.0f);
  }
}

// ---------- prologue C: children lists (transpose of parent lists) ----------
__global__ void k_p0c(float* ws)
{
  int j = blockIdx.x, b = blockIdx.y, lane = threadIdx.x;
  uint32_t* wsu = (uint32_t*)ws;
  unsigned long long* ws64 = (unsigned long long*)ws;
  uint8_t* cl = ((uint8_t*)&wsu[CL_OFF]) + (size_t)(b*N_ + j)*N_;
  int w = j >> 6; int sb = j & 63;
  int cnt = 0;
  #pragma unroll
  for (int m=0;m<4;m++){
    int t = m*64 + lane;
    unsigned long long rowm = ws64[TG64 + (size_t)(b*N_+t)*4 + w];
    bool p = ((rowm >> sb) & 1ULL) != 0ULL;
    unsigned long long bw = __ballot(p);
    if (p){
      int pos = cnt + (int)__popcll(bw & ((1ULL<<lane)-1ULL));
      cl[pos] = (uint8_t)t;
    }
    cnt += (int)__popcll(bw);
  }
  if (lane == 0) wsu[CC_OFF + b*N_ + j] = (uint32_t)cnt;
}

// ---------- pass 1: the sequential recurrence, 16 slice-blocks per batch ----------
__global__ void __launch_bounds__(192) k_pass1(const float* __restrict__ z,
    const float* __restrict__ Wih, const float* __restrict__ Whh,
    const float* __restrict__ bih_g, const float* __restrict__ bhh_g,
    float* ws)
{
  int bx = blockIdx.x;
  int b = bx & 7;
  if (b >= B_) return;            // idle blocks (XCD-mapping padding) exit
  int slice = bx >> 3;            // 0..15
  int tid = threadIdx.x;
  float* wsf = ws;
  uint32_t* wsu = (uint32_t*)ws;
  unsigned long long* ws64 = (unsigned long long*)ws;

  __shared__ __align__(16) float sh[H_];        // gathered full vector (h_prov in int2)
  __shared__ __align__(16) float sruns[H_];     // running sum of S rows
  __shared__ __align__(16) float sPS[N_*SC_];   // per-future-step parent-msg partial (matvec space)
  __shared__ __align__(16) float sa1[SC_];
  __shared__ __align__(16) float sa2[SC_];
  __shared__ __align__(16) float syy[SC_];
  __shared__ __align__(16) float sghz[SC_];
  __shared__ __align__(16) float sbih[SC_];
  __shared__ __align__(16) float sbhh[SC_];
  __shared__ __align__(16) float sdelta[SC_];

  const int g = tid >> 4;
  const int kc = tid & 15;

  // weight slices in registers: cols {gate*192 + slice*12 + cc}
  float rwih[12][4], rwhh[12][4];
  if (tid < MVT_){
    int gate = (4*g)/12, cc = (4*g)%12;
    int gcol = gate*H_ + slice*SH_ + cc;
    #pragma unroll
    for (int i=0;i<12;i++){
      int k = kc*12 + i;
      float4 a = *(const float4*)(Wih + (size_t)k*H3_ + gcol);
      rwih[i][0]=a.x; rwih[i][1]=a.y; rwih[i][2]=a.z; rwih[i][3]=a.w;
      float4 c = *(const float4*)(Whh + (size_t)k*H3_ + gcol);
      rwhh[i][0]=c.x; rwhh[i][1]=c.y; rwhh[i][2]=c.z; rwhh[i][3]=c.w;
    }
  }
  if (tid < SC_){
    int gate = tid/12, cc = tid%12;
    sbih[tid] = bih_g[gate*H_ + slice*SH_ + cc];
    sbhh[tid] = bhh_g[gate*H_ + slice*SH_ + cc];
  }
  if (tid < H_){ sh[tid] = z[b*H_ + tid]; sruns[tid] = 0.0f; }
  for (int i = tid; i < N_*SC_; i += 192) sPS[i] = 0.0f;
  float zreg = (tid < SH_) ? z[b*H_ + slice*SH_ + tid] : 0.0f;
  __syncthreads();

  // ghz = z@W_hh + b_hh (slice cols), constant over steps
  if (tid < MVT_){
    float a[4]; mv36_(sh, rwhh, kc, a);
    if (kc == 0){
      float4 bb = *(float4*)&sbhh[4*g];
      float4 o; o.x=a[0]+bb.x; o.y=a[1]+bb.y; o.z=a[2]+bb.z; o.w=a[3]+bb.w;
      *(float4*)&sghz[4*g] = o;
    }
  }
  // publish S(0) = h0 slice
  if (tid < 64){
    if (tid < SH_) wsf[sline_(b,0,slice) + tid] = wsf[H0_OFF + b*H_ + slice*SH_ + tid];
    __builtin_amdgcn_fence(__ATOMIC_RELEASE, "agent");
    if (tid == 0) __hip_atomic_store(&wsu[sline_(b,0,slice) + 12], 1u, __ATOMIC_RELEASE, __HIP_MEMORY_SCOPE_AGENT);
  }

  float qp0=0.f,qp1=0.f,qp2=0.f,qp3=0.f;   // previous q = runsum@W_ih (slice cols)
  float dginv_cur = wsf[DG_OFF + b*N_ + 1];
  unsigned long long tw0 = ws64[TG64 + (size_t)(b*N_+1)*4];
  float tflag_cur = (float)(tw0 & 1ULL);   // is (t-1) a parent of t, for t=1

  for (int t=1; t<N_; t++){
    // ======== int1: poll S(t-1), fold into runsum ========
    if (tid < 64){
      unsigned base = SL_OFF + (unsigned)((b*N_ + (t-1))*16)*16u;
      unsigned gofs = base + (unsigned)(tid&15)*16u + 12u;
      for(;;){
        uint32_t gv = 1u;
        if (tid < 16) gv = __hip_atomic_load(&wsu[gofs], __ATOMIC_ACQUIRE, __HIP_MEMORY_SCOPE_AGENT);
        if (__all(gv != 0u)) break;
      }
      __builtin_amdgcn_fence(__ATOMIC_ACQUIRE, "agent");
      if (tid < 48){
        int line = tid/3, q = tid%3;
        float4 d = *(const float4*)&wsf[base + (unsigned)line*16u + (unsigned)q*4u];
        int ho = line*12 + q*4;
        float4 r = *(float4*)&sruns[ho];
        r.x+=d.x; r.y+=d.y; r.z+=d.z; r.w+=d.w;
        *(float4*)&sruns[ho] = r;
      }
    }
    __syncthreads();
    // q = runsum@W_ih ; gx1 = q/t + b_ih ; gx2 = (PS[t] + flag*(q-qprev))*deginv + b_ih
    if (tid < MVT_){
      float nq[4]; mv36_(sruns, rwih, kc, nq);
      if (kc == 0){
        int c4 = 4*g;
        float4 bb = *(float4*)&sbih[c4];
        float4 pv = *(float4*)&sPS[t*SC_ + c4];
        float invt = 1.0f/(float)t;
        float4 dd; dd.x=nq[0]-qp0; dd.y=nq[1]-qp1; dd.z=nq[2]-qp2; dd.w=nq[3]-qp3;
        float4 o1; o1.x=nq[0]*invt+bb.x; o1.y=nq[1]*invt+bb.y; o1.z=nq[2]*invt+bb.z; o1.w=nq[3]*invt+bb.w;
        float4 o2;
        o2.x=(pv.x + tflag_cur*dd.x)*dginv_cur + bb.x;
        o2.y=(pv.y + tflag_cur*dd.y)*dginv_cur + bb.y;
        o2.z=(pv.z + tflag_cur*dd.z)*dginv_cur + bb.z;
        o2.w=(pv.w + tflag_cur*dd.w)*dginv_cur + bb.w;
        *(float4*)&sa1[c4]=o1; *(float4*)&sa2[c4]=o2; *(float4*)&sdelta[c4]=dd;
      }
      qp0=nq[0]; qp1=nq[1]; qp2=nq[2]; qp3=nq[3];
    }
    __syncthreads();
    // wave0: h_prov slice, publish H(t), poll H(t), gather full h_prov
    if (tid < 64){
      if (tid < SH_){
        float r = sigm_(sa1[tid] + sghz[tid]);
        float u = sigm_(sa1[SH_+tid] + sghz[SH_+tid]);
        float n = tanh_(sa1[2*SH_+tid] + r*sghz[2*SH_+tid]);
        float hp = (1.0f-u)*n + u*zreg;
        wsf[hline_(b,t,slice) + tid] = hp;
      }
      __builtin_amdgcn_fence(__ATOMIC_RELEASE, "agent");
      if (tid == 0) __hip_atomic_store(&wsu[hline_(b,t,slice)+12], 1u, __ATOMIC_RELEASE, __HIP_MEMORY_SCOPE_AGENT);
      unsigned hbase = HL_OFF + (unsigned)((b*N_ + t)*16)*16u;
      unsigned gofs = hbase + (unsigned)(tid&15)*16u + 12u;
      for(;;){
        uint32_t gv = 1u;
        if (tid < 16) gv = __hip_atomic_load(&wsu[gofs], __ATOMIC_ACQUIRE, __HIP_MEMORY_SCOPE_AGENT);
        if (__all(gv != 0u)) break;
      }
      __builtin_amdgcn_fence(__ATOMIC_ACQUIRE, "agent");
      if (tid < 48){
        int line = tid/3, q = tid%3;
        float4 d = *(const float4*)&wsf[hbase + (unsigned)line*16u + (unsigned)q*4u];
        *(float4*)&sh[line*12 + q*4] = d;
      }
    } else {
      // waves 1-2: scatter delta = S(t-1)@W_ih into PS of future children of node t-1
      int ccn = (int)wsu[CC_OFF + b*N_ + (t-1)];
      const uint8_t* cl = ((const uint8_t*)&wsu[CL_OFF]) + (size_t)(b*N_ + (t-1))*N_;
      for (int i = tid - 64; i < ccn; i += 128){
        int tc = cl[i];
        if (tc != t){
          #pragma unroll
          for (int m=0;m<9;m++){
            float4 v = *(float4*)&sPS[tc*SC_ + 4*m];
            float4 d = *(float4*)&sdelta[4*m];
            v.x+=d.x; v.y+=d.y; v.z+=d.z; v.w+=d.w;
            *(float4*)&sPS[tc*SC_ + 4*m] = v;
          }
        }
      }
    }
    __syncthreads();
    // ======== int2: gh2 = h_prov@W_hh ========
    if (tid < MVT_){
      float a[4]; mv36_(sh, rwhh, kc, a);
      if (kc == 0){
        float4 o; o.x=a[0]; o.y=a[1]; o.z=a[2]; o.w=a[3];
        *(float4*)&syy[4*g] = o;
      }
    }
    __syncthreads();
    if (tid < 64){
      if (tid < SH_){
        float gr = syy[tid] + sbhh[tid];
        float gu = syy[SH_+tid] + sbhh[SH_+tid];
        float gn = syy[2*SH_+tid] + sbhh[2*SH_+tid];
        float r2 = sigm_(sa2[tid] + gr);
        float u2 = sigm_(sa2[SH_+tid] + gu);
        float n2 = tanh_(sa2[2*SH_+tid] + r2*gn);
        float hn = (1.0f-u2)*n2 + u2*sh[slice*SH_ + tid];
        wsf[sline_(b,t,slice) + tid] = hn;
      }
      __builtin_amdgcn_fence(__ATOMIC_RELEASE, "agent");
      if (tid == 0) __hip_atomic_store(&wsu[sline_(b,t,slice)+12], 1u, __ATOMIC_RELEASE, __HIP_MEMORY_SCOPE_AGENT);
      // A-row duty, rotated across slices (off critical path)
      if (slice == (t & 15) && tid < 4){
        int npt = (int)wsu[PC_OFF + b*N_ + t];
        const uint8_t* pb = ((const uint8_t*)&wsu[PL_OFF]) + (size_t)(b*N_ + t)*N_;
        unsigned long long acc = 0ULL;
        for (int i=0;i<npt;i++){
          int p = pb[i];
          acc |= ws64[AB64 + (size_t)(b*N_ + p)*4 + tid];
        }
        ws64[AN64 + (size_t)(b*N_+t)*4 + tid] = acc;
        ws64[AB64 + (size_t)(b*N_+t)*4 + tid] = acc | ws64[TG64 + (size_t)(b*N_+t)*4 + tid];
      }
    }
    if (t < N_-1){
      dginv_cur = wsf[DG_OFF + b*N_ + t + 1];
      unsigned long long tw = ws64[TG64 + (size_t)(b*N_ + t + 1)*4 + (t>>6)];
      tflag_cur = (float)((tw >> (t & 63)) & 1ULL);
    }
  }
}

// ---------- pass 2a: G = S@W1b, C = Hprov@W1a + zc, NF = S@Wf + bf ----------
__global__ void k_p2a(const float* __restrict__ W1, const float* __restrict__ Wf,
    const float* __restrict__ bf, float* ws, float* out)
{
  int j = blockIdx.x, b = blockIdx.y, tid = threadIdx.x;
  __shared__ float srow[H_], hrow[H_];
  __shared__ float nfp[3][F_];
  int lofs = (tid/12)*16 + (tid%12);
  srow[tid] = ws[SL_OFF + (unsigned)((b*N_+j)*16)*16u + lofs];
  hrow[tid] = ws[HL_OFF + (unsigned)((b*N_+j)*16)*16u + lofs];   // garbage for j=0, C[0] unused
  __syncthreads();
  float accG = 0.f, accC = 0.f;
  for (int k=0;k<H_;k++){
    float sv = srow[k], hv = hrow[k];
    accG += sv * W1[(size_t)(H_+k)*H_ + tid];
    accC += hv * W1[(size_t)k*H_ + tid];
  }
  ws[G_OFF + (size_t)(b*N_+j)*H_ + tid] = accG;
  ws[C_OFF + (size_t)(b*N_+j)*H_ + tid] = accC + ws[ZC_OFF + b*H_ + tid];
  int f = tid & 63, kp = tid >> 6;
  float a = 0.f;
  for (int i=0;i<64;i++){ int k = kp*64 + i; a += srow[k]*Wf[(size_t)k*F_ + f]; }
  nfp[kp][f] = a;
  __syncthreads();
  if (tid < F_) out[NF_OUT + (size_t)(b*N_+j)*F_ + tid] = nfp[0][tid]+nfp[1][tid]+nfp[2][tid] + bf[tid];
}

// ---------- pass 2b: log-likelihood ----------
__global__ void __launch_bounds__(256) k_p2b(const float* __restrict__ W2,
    const float* __restrict__ b2p, float* ws, float* out)
{
  int t = blockIdx.x + 1, b = blockIdx.y;
  int tid = threadIdx.x; int lane = tid & 63; int wv = tid >> 6;
  __shared__ float cvec[H_], sw2[H_];
  __shared__ float wsum[4];
  __shared__ unsigned long long sanc[4], stgt[4];
  unsigned long long* ws64 = (unsigned long long*)ws;
  if (tid < H_){
    cvec[tid] = ws[C_OFF + (size_t)(b*N_+t)*H_ + tid];
    sw2[tid] = W2[tid];
  }
  if (tid < 4){
    sanc[tid] = ws64[AN64 + (size_t)(b*N_+t)*4 + tid];
    stgt[tid] = ws64[TG64 + (size_t)(b*N_+t)*4 + tid];
  }
  __syncthreads();
  float b2s = b2p[0];
  float c0 = cvec[lane], c1 = cvec[64+lane], c2 = cvec[128+lane];
  float w20 = sw2[lane], w21 = sw2[64+lane], w22 = sw2[128+lane];
  const float* Gb = ws + G_OFF + (size_t)(b*N_)*H_;
  float acc = 0.f;
  for (int j = wv; j < t; j += 4){
    const float* gr = Gb + (size_t)j*H_;
    float p0 = fmaxf(c0 + gr[lane], 0.f)*w20
             + fmaxf(c1 + gr[64+lane], 0.f)*w21
             + fmaxf(c2 + gr[128+lane], 0.f)*w22;
    #pragma unroll
    for (int m=32;m>=1;m>>=1) p0 += __shfl_xor(p0, m);
    if (lane == 0){
      float logit = p0 + b2s;
      float pp = 1.0f/(1.0f+__expf(-logit));
      float anc = (float)((sanc[j>>6] >> (j&63)) & 1ULL);
      pp = pp * (1.0f - anc);
      pp = fminf(fmaxf(pp, 1e-6f), 1.0f - 1e-6f);
      int tg = (int)((stgt[j>>6] >> (j&63)) & 1ULL);
      acc += tg ? logf(pp) : log1pf(-pp);
    }
  }
  if (lane == 0) wsum[wv] = acc;
  __syncthreads();
  if (tid == 0) atomicAdd(out + LL_OUT, wsum[0]+wsum[1]+wsum[2]+wsum[3]);
}

extern "C" void kernel_launch(void* const* d_in, const int* in_sizes, int n_in,
                              void* d_out, int out_size, void* d_ws, size_t ws_size,
                              hipStream_t stream) {
  (void)in_sizes; (void)n_in; (void)out_size; (void)ws_size;
  const float* z     = (const float*)d_in[0];
  const float* tgt   = (const float*)d_in[1];
  const float* Winit = (const float*)d_in[2];
  const float* binit = (const float*)d_in[3];
  const float* Wih   = (const float*)d_in[4];
  const float* Whh   = (const float*)d_in[5];
  const float* bih   = (const float*)d_in[6];
  const float* bhh   = (const float*)d_in[7];
  const float* W1    = (const float*)d_in[8];
  const float* b1    = (const float*)d_in[9];
  const float* W2    = (const float*)d_in[10];
  const float* b2    = (const float*)d_in[11];
  const float* Wf    = (const float*)d_in[12];
  const float* bf    = (const float*)d_in[13];
  float* out = (float*)d_out;
  float* ws  = (float*)d_ws;

  // Output 0: L = teacher_forcing_targets (verbatim copy)
  hipMemcpyAsync(d_out, d_in[1], (size_t)B_*N_*N_*sizeof(float), hipMemcpyDeviceToDevice, stream);

  k_p0a<<<dim3(B_), dim3(H_), 0, stream>>>(z, Winit, binit, W1, b1, ws, out);
  k_p0b<<<dim3(N_, B_), dim3(64), 0, stream>>>(tgt, ws);
  k_p0c<<<dim3(N_, B_), dim3(64), 0, stream>>>(ws);
  k_pass1<<<dim3(128), dim3(192), 0, stream>>>(z, Wih, Whh, bih, bhh, ws);
  k_p2a<<<dim3(N_, B_), dim3(H_), 0, stream>>>(W1, Wf, bf, ws, out);
  k_p2b<<<dim3(N_-1, B_), dim3(256), 0, stream>>>(W2, b2, ws, out);
}

// Round 2
// 1434.361 us; speedup vs baseline: 2.3838x; 2.3838x over previous
//
#include <hip/hip_runtime.h>
#include <stdint.h>

#define B_ 4
#define N_ 256
#define H_ 192
#define H3_ 576
#define F_ 64
#define SH_ 12      // hidden per slice (16 slices)
#define SC_ 36      // 3 gates * SH_
#define MVT_ 144    // 9 col-groups * 16 k-chunks

// ---- workspace layout (32-bit words) ----
#define H0_OFF   0u
#define ZC_OFF   1024u
#define HL_OFF   2048u       // [b][t][192] h_prov rows (12 floats per slice, packed)
#define SL_OFF   198656u     // [b][t][192] S rows
#define AN_OFF   395264u     // [b][t][4] u64 ancestor masks
#define TG_OFF   403456u     // [b][t][4] u64 target masks
#define PL_OFF   411648u     // parent lists (u8)
#define PC_OFF   477184u     // parent counts
#define DG_OFF   478208u     // 1/deg
#define G_OFF    479232u     // S@W1b
#define C_OFF    675840u     // Hprov@W1a + zc
#define CL_OFF   872448u     // children lists (u8)
#define CC_OFF   937984u     // children counts
#define SGEN_OFF 939008u     // [b][t][16] gen words for S rows
#define HGEN_OFF 955392u     // [b][t][16] gen words for Hprov rows

#define AN64 (AN_OFF/2)
#define TG64 (TG_OFF/2)

#define NF_OUT 262144u
#define LL_OUT 327680u

__device__ __forceinline__ float sigm_(float x){ return 1.0f/(1.0f + __expf(-x)); }
__device__ __forceinline__ float tanh_(float x){
  float ax = fabsf(x);
  float e = __expf(-2.0f*ax);
  float t = (1.0f - e)/(1.0f + e);
  return x < 0.0f ? -t : t;
}

// relaxed agent-scope (sc1) 64-bit payload ops: bypass per-XCD L2, serviced at MALL.
__device__ __forceinline__ void st64_(float* p, float2 v){
  __hip_atomic_store((unsigned long long*)p, __builtin_bit_cast(unsigned long long, v),
                     __ATOMIC_RELAXED, __HIP_MEMORY_SCOPE_AGENT);
}
__device__ __forceinline__ float2 ld64_(const float* p){
  unsigned long long u = __hip_atomic_load((const unsigned long long*)p,
                     __ATOMIC_RELAXED, __HIP_MEMORY_SCOPE_AGENT);
  return __builtin_bit_cast(float2, u);
}

// y[36] = x[192] @ Wslice ; 144 threads: g=tid>>4 owns 4 cols, kc=tid&15 owns 12 k's.
__device__ __forceinline__ void mv36_(const float* x, const float (&w)[12][4], int kc, float acc[4]){
  acc[0]=0.f; acc[1]=0.f; acc[2]=0.f; acc[3]=0.f;
  #pragma unroll
  for (int i=0;i<12;i++){
    float xv = x[kc*12+i];
    acc[0] += xv*w[i][0];
    acc[1] += xv*w[i][1];
    acc[2] += xv*w[i][2];
    acc[3] += xv*w[i][3];
  }
  #pragma unroll
  for (int m=1;m<16;m<<=1){
    acc[0] += __shfl_xor(acc[0], m);
    acc[1] += __shfl_xor(acc[1], m);
    acc[2] += __shfl_xor(acc[2], m);
    acc[3] += __shfl_xor(acc[3], m);
  }
}

// ---------- prologue A: h0 = tanh(z@W_init+b_init), zc = z@W1c+b1, zero ll ----------
__global__ void k_p0a(const float* __restrict__ z, const float* __restrict__ Winit,
    const float* __restrict__ binit, const float* __restrict__ W1, const float* __restrict__ b1,
    float* ws, float* out)
{
  int b = blockIdx.x; int tid = threadIdx.x;
  __shared__ float zs[H_];
  zs[tid] = z[b*H_ + tid];
  __syncthreads();
  float a0=0.f, a1=0.f;
  for (int k=0;k<H_;k++){
    float zv = zs[k];
    a0 += zv * Winit[(size_t)k*H_ + tid];
    a1 += zv * W1[(size_t)(2*H_ + k)*H_ + tid];   // W1c rows 384..575
  }
  ws[H0_OFF + b*H_ + tid] = tanh_(a0 + binit[tid]);
  ws[ZC_OFF + b*H_ + tid] = a1 + b1[tid];
  if (b==0 && tid==0) out[LL_OUT] = 0.0f;
}

// ---------- prologue B: per-row parent lists, tgt bitmasks, deg ----------
__global__ void k_p0b(const float* __restrict__ tgt, float* ws)
{
  int t = blockIdx.x, b = blockIdx.y, lane = threadIdx.x;
  uint32_t* wsu = (uint32_t*)ws;
  unsigned long long* ws64 = (unsigned long long*)ws;
  const float* row = tgt + ((size_t)(b*N_) + t)*N_;
  uint8_t* pl = ((uint8_t*)&wsu[PL_OFF]) + (size_t)(b*N_ + t)*N_;
  int cnt = 0;
  #pragma unroll
  for (int m=0;m<4;m++){
    float v = row[m*64 + lane];
    bool p = (v != 0.0f);
    unsigned long long bw = __ballot(p);
    if (lane == 0) ws64[TG64 + (size_t)(b*N_+t)*4 + m] = bw;
    if (p){
      int pos = cnt + (int)__popcll(bw & ((1ULL<<lane)-1ULL));
      pl[pos] = (uint8_t)(m*64 + lane);
    }
    cnt += (int)__popcll(bw);
  }
  if (lane == 0){
    wsu[PC_OFF + b*N_ + t] = (uint32_t)cnt;
    ws[DG_OFF + b*N_ + t] = 1.0f / fmaxf((float)cnt, 1.0f);
  }
}

// ---------- prologue C: children lists (transpose of parent lists) ----------
__global__ void k_p0c(float* ws)
{
  int j = blockIdx.x, b = blockIdx.y, lane = threadIdx.x;
  uint32_t* wsu = (uint32_t*)ws;
  unsigned long long* ws64 = (unsigned long long*)ws;
  uint8_t* cl = ((uint8_t*)&wsu[CL_OFF]) + (size_t)(b*N_ + j)*N_;
  int w = j >> 6; int sb = j & 63;
  int cnt = 0;
  #pragma unroll
  for (int m=0;m<4;m++){
    int t = m*64 + lane;
    unsigned long long rowm = ws64[TG64 + (size_t)(b*N_+t)*4 + w];
    bool p = ((rowm >> sb) & 1ULL) != 0ULL;
    unsigned long long bw = __ballot(p);
    if (p){
      int pos = cnt + (int)__popcll(bw & ((1ULL<<lane)-1ULL));
      cl[pos] = (uint8_t)t;
    }
    cnt += (int)__popcll(bw);
  }
  if (lane == 0) wsu[CC_OFF + b*N_ + j] = (uint32_t)cnt;
}

// ---------- ancestor chain: depends only on targets; fully decoupled from pass1 ----------
__global__ void k_anc(float* ws)
{
  int b = blockIdx.x; int lane = threadIdx.x;   // 64 threads, 1 wave
  unsigned long long* ws64 = (unsigned long long*)ws;
  uint32_t* wsu = (uint32_t*)ws;
  __shared__ unsigned long long AB[N_][4];
  if (lane < 4) AB[0][lane] = 0ULL;
  __syncthreads();
  int wq = lane & 3, pg = lane >> 2;            // 4 words x 16 parent groups
  for (int t=1; t<N_; t++){
    int npt = (int)wsu[PC_OFF + b*N_ + t];
    const uint8_t* pb = ((const uint8_t*)&wsu[PL_OFF]) + (size_t)(b*N_+t)*N_;
    unsigned long long acc = 0ULL;
    for (int i=pg; i<npt; i+=16) acc |= AB[pb[i]][wq];
    #pragma unroll
    for (int m=4; m<64; m<<=1) acc |= __shfl_xor(acc, m);
    if (lane < 4){
      ws64[AN64 + (size_t)(b*N_+t)*4 + lane] = acc;
      AB[t][lane] = acc | ws64[TG64 + (size_t)(b*N_+t)*4 + lane];
    }
    __syncthreads();
  }
}

// ---------- pass 1: sequential recurrence, 16 slice-blocks per batch ----------
// All cross-block words are relaxed agent-scope atomics (sc1 -> MALL). No fences,
// no buffer_wbl2/buffer_inv storms. Publish protocol: payload sc1 stores ->
// s_waitcnt vmcnt(0) -> gen sc1 store (tag = step id; 0xAA poison never matches).
__global__ void __launch_bounds__(192) k_pass1(const float* __restrict__ z,
    const float* __restrict__ Wih, const float* __restrict__ Whh,
    const float* __restrict__ bih_g, const float* __restrict__ bhh_g,
    float* ws)
{
  int bx = blockIdx.x;
  int b = bx & 7;
  if (b >= B_) return;
  int slice = bx >> 3;
  int tid = threadIdx.x;
  float* wsf = ws;
  uint32_t* wsu = (uint32_t*)ws;
  unsigned long long* ws64 = (unsigned long long*)ws;

  __shared__ __align__(16) float sh[H_];
  __shared__ __align__(16) float sruns[H_];
  __shared__ __align__(16) float sPS[N_*SC_];
  __shared__ __align__(16) float sa1[SC_];
  __shared__ __align__(16) float sa2[SC_];
  __shared__ __align__(16) float syy[SC_];
  __shared__ __align__(16) float sghz[SC_];
  __shared__ __align__(16) float sbih[SC_];
  __shared__ __align__(16) float sbhh[SC_];
  __shared__ __align__(16) float sdelta[SC_];

  const int g = tid >> 4;
  const int kc = tid & 15;

  float rwih[12][4], rwhh[12][4];
  if (tid < MVT_){
    int gate = (4*g)/12, cc = (4*g)%12;
    int gcol = gate*H_ + slice*SH_ + cc;
    #pragma unroll
    for (int i=0;i<12;i++){
      int k = kc*12 + i;
      float4 a = *(const float4*)(Wih + (size_t)k*H3_ + gcol);
      rwih[i][0]=a.x; rwih[i][1]=a.y; rwih[i][2]=a.z; rwih[i][3]=a.w;
      float4 c = *(const float4*)(Whh + (size_t)k*H3_ + gcol);
      rwhh[i][0]=c.x; rwhh[i][1]=c.y; rwhh[i][2]=c.z; rwhh[i][3]=c.w;
    }
  }
  if (tid < SC_){
    int gate = tid/12, cc = tid%12;
    sbih[tid] = bih_g[gate*H_ + slice*SH_ + cc];
    sbhh[tid] = bhh_g[gate*H_ + slice*SH_ + cc];
  }
  if (tid < H_){ sh[tid] = z[b*H_ + tid]; sruns[tid] = 0.0f; }
  for (int i = tid; i < N_*SC_; i += 192) sPS[i] = 0.0f;
  float zreg = (tid < SH_) ? z[b*H_ + slice*SH_ + tid] : 0.0f;
  __syncthreads();

  // ghz = z@W_hh + b_hh (slice cols), constant over steps
  if (tid < MVT_){
    float a[4]; mv36_(sh, rwhh, kc, a);
    if (kc == 0){
      float4 bb = *(float4*)&sbhh[4*g];
      float4 o; o.x=a[0]+bb.x; o.y=a[1]+bb.y; o.z=a[2]+bb.z; o.w=a[3]+bb.w;
      *(float4*)&sghz[4*g] = o;
    }
  }
  // publish S(0) = h0 slice  (gen tag = 1)
  if (tid < 64){
    if (tid < 6){
      float2 v = *(const float2*)&wsf[H0_OFF + b*H_ + slice*SH_ + 2*tid];
      st64_(&wsf[SL_OFF + (unsigned)(b*N_)*192u + (unsigned)slice*12u + 2u*tid], v);
    }
    asm volatile("s_waitcnt vmcnt(0)" ::: "memory");
    if (tid == 0)
      __hip_atomic_store(&wsu[SGEN_OFF + (unsigned)(b*N_)*16u + slice], 1u,
                         __ATOMIC_RELAXED, __HIP_MEMORY_SCOPE_AGENT);
  }

  float qp0=0.f,qp1=0.f,qp2=0.f,qp3=0.f;
  float dginv_cur = wsf[DG_OFF + b*N_ + 1];
  unsigned long long tw0 = ws64[TG64 + (size_t)(b*N_+1)*4];
  float tflag_cur = (float)(tw0 & 1ULL);

  for (int t=1; t<N_; t++){
    const uint32_t tagS = (uint32_t)t;       // S(t-1) ready
    const uint32_t tagH = (uint32_t)(t+1);   // H(t) / S(t) ready
    float hp = 0.f;
    // ======== poll S(t-1), fold into runsum (wave0 only) ========
    if (tid < 64){
      unsigned sg = SGEN_OFF + (unsigned)(b*N_ + (t-1))*16u;
      uint32_t gv;
      do {
        gv = (tid < 16) ? __hip_atomic_load(&wsu[sg + (unsigned)tid],
                  __ATOMIC_RELAXED, __HIP_MEMORY_SCOPE_AGENT) : tagS;
      } while (__all(gv == tagS) == 0);
      __builtin_amdgcn_fence(__ATOMIC_ACQUIRE, "workgroup");  // compiler barrier only
      unsigned sbase = SL_OFF + (unsigned)(b*N_ + (t-1))*192u;
      float2 v = ld64_(&wsf[sbase + 2u*tid]);
      float2 r = *(float2*)&sruns[2*tid];
      r.x += v.x; r.y += v.y;
      *(float2*)&sruns[2*tid] = r;
      if (tid < 32){
        float2 w = ld64_(&wsf[sbase + 128u + 2u*tid]);
        float2 r2 = *(float2*)&sruns[128+2*tid];
        r2.x += w.x; r2.y += w.y;
        *(float2*)&sruns[128+2*tid] = r2;
      }
    }
    __syncthreads();
    // q = runsum@W_ih ; gx1 = q/t + b_ih ; gx2 = (PS[t] + flag*(q-qprev))*deginv + b_ih
    if (tid < MVT_){
      float nq[4]; mv36_(sruns, rwih, kc, nq);
      if (kc == 0){
        int c4 = 4*g;
        float4 bb = *(float4*)&sbih[c4];
        float4 pv = *(float4*)&sPS[t*SC_ + c4];
        float invt = 1.0f/(float)t;
        float4 dd; dd.x=nq[0]-qp0; dd.y=nq[1]-qp1; dd.z=nq[2]-qp2; dd.w=nq[3]-qp3;
        float4 o1; o1.x=nq[0]*invt+bb.x; o1.y=nq[1]*invt+bb.y; o1.z=nq[2]*invt+bb.z; o1.w=nq[3]*invt+bb.w;
        float4 o2;
        o2.x=(pv.x + tflag_cur*dd.x)*dginv_cur + bb.x;
        o2.y=(pv.y + tflag_cur*dd.y)*dginv_cur + bb.y;
        o2.z=(pv.z + tflag_cur*dd.z)*dginv_cur + bb.z;
        o2.w=(pv.w + tflag_cur*dd.w)*dginv_cur + bb.w;
        *(float4*)&sa1[c4]=o1; *(float4*)&sa2[c4]=o2; *(float4*)&sdelta[c4]=dd;
      }
      qp0=nq[0]; qp1=nq[1]; qp2=nq[2]; qp3=nq[3];
    }
    __syncthreads();
    // wave0: h_prov slice -> publish H(t) -> poll -> gather full h_prov
    if (tid < 64){
      if (tid < SH_){
        float r = sigm_(sa1[tid] + sghz[tid]);
        float u = sigm_(sa1[SH_+tid] + sghz[SH_+tid]);
        float n = tanh_(sa1[2*SH_+tid] + r*sghz[2*SH_+tid]);
        hp = (1.0f-u)*n + u*zreg;
      }
      float lo = __shfl(hp, 2*tid);
      float hi = __shfl(hp, 2*tid+1);
      unsigned hbase = HL_OFF + (unsigned)(b*N_ + t)*192u;
      if (tid < 6){
        float2 v; v.x = lo; v.y = hi;
        st64_(&wsf[hbase + (unsigned)slice*12u + 2u*tid], v);
      }
      asm volatile("s_waitcnt vmcnt(0)" ::: "memory");
      if (tid == 0)
        __hip_atomic_store(&wsu[HGEN_OFF + (unsigned)(b*N_+t)*16u + slice], tagH,
                           __ATOMIC_RELAXED, __HIP_MEMORY_SCOPE_AGENT);
      unsigned hg = HGEN_OFF + (unsigned)(b*N_+t)*16u;
      uint32_t gv;
      do {
        gv = (tid < 16) ? __hip_atomic_load(&wsu[hg + (unsigned)tid],
                  __ATOMIC_RELAXED, __HIP_MEMORY_SCOPE_AGENT) : tagH;
      } while (__all(gv == tagH) == 0);
      __builtin_amdgcn_fence(__ATOMIC_ACQUIRE, "workgroup");
      float2 v2 = ld64_(&wsf[hbase + 2u*tid]);
      *(float2*)&sh[2*tid] = v2;
      if (tid < 32){
        float2 v3 = ld64_(&wsf[hbase + 128u + 2u*tid]);
        *(float2*)&sh[128+2*tid] = v3;
      }
    } else {
      // waves 1-2: scatter delta = S(t-1)@W_ih into PS of future children of node t-1
      int ccn = (int)wsu[CC_OFF + b*N_ + (t-1)];
      const uint8_t* cl = ((const uint8_t*)&wsu[CL_OFF]) + (size_t)(b*N_ + (t-1))*N_;
      for (int i = tid - 64; i < ccn; i += 128){
        int tc = cl[i];
        if (tc != t){
          #pragma unroll
          for (int m=0;m<9;m++){
            float4 v = *(float4*)&sPS[tc*SC_ + 4*m];
            float4 d = *(float4*)&sdelta[4*m];
            v.x+=d.x; v.y+=d.y; v.z+=d.z; v.w+=d.w;
            *(float4*)&sPS[tc*SC_ + 4*m] = v;
          }
        }
      }
    }
    __syncthreads();
    // gh2 = h_prov@W_hh
    if (tid < MVT_){
      float a[4]; mv36_(sh, rwhh, kc, a);
      if (kc == 0){
        float4 o; o.x=a[0]; o.y=a[1]; o.z=a[2]; o.w=a[3];
        *(float4*)&syy[4*g] = o;
      }
    }
    __syncthreads();
    // h_new slice -> publish S(t)
    if (tid < 64){
      float hn = 0.f;
      if (tid < SH_){
        float gr = syy[tid] + sbhh[tid];
        float gu = syy[SH_+tid] + sbhh[SH_+tid];
        float gn = syy[2*SH_+tid] + sbhh[2*SH_+tid];
        float r2 = sigm_(sa2[tid] + gr);
        float u2 = sigm_(sa2[SH_+tid] + gu);
        float n2 = tanh_(sa2[2*SH_+tid] + r2*gn);
        hn = (1.0f-u2)*n2 + u2*hp;
      }
      float lo = __shfl(hn, 2*tid);
      float hi = __shfl(hn, 2*tid+1);
      if (tid < 6){
        float2 v; v.x = lo; v.y = hi;
        st64_(&wsf[SL_OFF + (unsigned)(b*N_+t)*192u + (unsigned)slice*12u + 2u*tid], v);
      }
      asm volatile("s_waitcnt vmcnt(0)" ::: "memory");
      if (tid == 0)
        __hip_atomic_store(&wsu[SGEN_OFF + (unsigned)(b*N_+t)*16u + slice], tagH,
                           __ATOMIC_RELAXED, __HIP_MEMORY_SCOPE_AGENT);
    }
    if (t < N_-1){
      dginv_cur = wsf[DG_OFF + b*N_ + t + 1];
      unsigned long long tw = ws64[TG64 + (size_t)(b*N_ + t + 1)*4 + (t>>6)];
      tflag_cur = (float)((tw >> (t & 63)) & 1ULL);
    }
  }
}

// ---------- pass 2a: G = S@W1b, C = Hprov@W1a + zc, NF = S@Wf + bf ----------
__global__ void k_p2a(const float* __restrict__ W1, const float* __restrict__ Wf,
    const float* __restrict__ bf, float* ws, float* out)
{
  int j = blockIdx.x, b = blockIdx.y, tid = threadIdx.x;
  __shared__ float srow[H_], hrow[H_];
  __shared__ float nfp[3][F_];
  srow[tid] = ws[SL_OFF + (unsigned)(b*N_+j)*192u + tid];
  hrow[tid] = ws[HL_OFF + (unsigned)(b*N_+j)*192u + tid];   // garbage for j=0, C[0] unused
  __syncthreads();
  float accG = 0.f, accC = 0.f;
  for (int k=0;k<H_;k++){
    float sv = srow[k], hv = hrow[k];
    accG += sv * W1[(size_t)(H_+k)*H_ + tid];
    accC += hv * W1[(size_t)k*H_ + tid];
  }
  ws[G_OFF + (size_t)(b*N_+j)*H_ + tid] = accG;
  ws[C_OFF + (size_t)(b*N_+j)*H_ + tid] = accC + ws[ZC_OFF + b*H_ + tid];
  int f = tid & 63, kp = tid >> 6;
  float a = 0.f;
  for (int i=0;i<64;i++){ int k = kp*64 + i; a += srow[k]*Wf[(size_t)k*F_ + f]; }
  nfp[kp][f] = a;
  __syncthreads();
  if (tid < F_) out[NF_OUT + (size_t)(b*N_+j)*F_ + tid] = nfp[0][tid]+nfp[1][tid]+nfp[2][tid] + bf[tid];
}

// ---------- pass 2b: log-likelihood ----------
__global__ void __launch_bounds__(256) k_p2b(const float* __restrict__ W2,
    const float* __restrict__ b2p, float* ws, float* out)
{
  int t = blockIdx.x + 1, b = blockIdx.y;
  int tid = threadIdx.x; int lane = tid & 63; int wv = tid >> 6;
  __shared__ float cvec[H_], sw2[H_];
  __shared__ float wsum[4];
  __shared__ unsigned long long sanc[4], stgt[4];
  unsigned long long* ws64 = (unsigned long long*)ws;
  if (tid < H_){
    cvec[tid] = ws[C_OFF + (size_t)(b*N_+t)*H_ + tid];
    sw2[tid] = W2[tid];
  }
  if (tid < 4){
    sanc[tid] = ws64[AN64 + (size_t)(b*N_+t)*4 + tid];
    stgt[tid] = ws64[TG64 + (size_t)(b*N_+t)*4 + tid];
  }
  __syncthreads();
  float b2s = b2p[0];
  float c0 = cvec[lane], c1 = cvec[64+lane], c2 = cvec[128+lane];
  float w20 = sw2[lane], w21 = sw2[64+lane], w22 = sw2[128+lane];
  const float* Gb = ws + G_OFF + (size_t)(b*N_)*H_;
  float acc = 0.f;
  for (int j = wv; j < t; j += 4){
    const float* gr = Gb + (size_t)j*H_;
    float p0 = fmaxf(c0 + gr[lane], 0.f)*w20
             + fmaxf(c1 + gr[64+lane], 0.f)*w21
             + fmaxf(c2 + gr[128+lane], 0.f)*w22;
    #pragma unroll
    for (int m=32;m>=1;m>>=1) p0 += __shfl_xor(p0, m);
    if (lane == 0){
      float logit = p0 + b2s;
      float pp = 1.0f/(1.0f+__expf(-logit));
      float anc = (float)((sanc[j>>6] >> (j&63)) & 1ULL);
      pp = pp * (1.0f - anc);
      pp = fminf(fmaxf(pp, 1e-6f), 1.0f - 1e-6f);
      int tg = (int)((stgt[j>>6] >> (j&63)) & 1ULL);
      acc += tg ? logf(pp) : log1pf(-pp);
    }
  }
  if (lane == 0) wsum[wv] = acc;
  __syncthreads();
  if (tid == 0) atomicAdd(out + LL_OUT, wsum[0]+wsum[1]+wsum[2]+wsum[3]);
}

extern "C" void kernel_launch(void* const* d_in, const int* in_sizes, int n_in,
                              void* d_out, int out_size, void* d_ws, size_t ws_size,
                              hipStream_t stream) {
  (void)in_sizes; (void)n_in; (void)out_size; (void)ws_size;
  const float* z     = (const float*)d_in[0];
  const float* tgt   = (const float*)d_in[1];
  const float* Winit = (const float*)d_in[2];
  const float* binit = (const float*)d_in[3];
  const float* Wih   = (const float*)d_in[4];
  const float* Whh   = (const float*)d_in[5];
  const float* bih   = (const float*)d_in[6];
  const float* bhh   = (const float*)d_in[7];
  const float* W1    = (const float*)d_in[8];
  const float* b1    = (const float*)d_in[9];
  const float* W2    = (const float*)d_in[10];
  const float* b2    = (const float*)d_in[11];
  const float* Wf    = (const float*)d_in[12];
  const float* bf    = (const float*)d_in[13];
  float* out = (float*)d_out;
  float* ws  = (float*)d_ws;

  // Output 0: L = teacher_forcing_targets (verbatim copy)
  hipMemcpyAsync(d_out, d_in[1], (size_t)B_*N_*N_*sizeof(float), hipMemcpyDeviceToDevice, stream);

  k_p0a<<<dim3(B_), dim3(H_), 0, stream>>>(z, Winit, binit, W1, b1, ws, out);
  k_p0b<<<dim3(N_, B_), dim3(64), 0, stream>>>(tgt, ws);
  k_p0c<<<dim3(N_, B_), dim3(64), 0, stream>>>(ws);
  k_anc<<<dim3(B_), dim3(64), 0, stream>>>(ws);
  k_pass1<<<dim3(128), dim3(192), 0, stream>>>(z, Wih, Whh, bih, bhh, ws);
  k_p2a<<<dim3(N_, B_), dim3(H_), 0, stream>>>(W1, Wf, bf, ws, out);
  k_p2b<<<dim3(N_-1, B_), dim3(256), 0, stream>>>(W2, b2, ws, out);
}